// Round 2
// baseline (1144.594 us; speedup 1.0000x reference)
//
#include <hip/hip_runtime.h>
#include <math.h>

#define NTOK   32768
#define DIM    2048
#define NE     256
#define NG     8
#define GSZ    32
#define NLIM   4
#define TOPK   8
#define RSCALE 2.5f
#define TAU    4e-7f

#define BT      128   // tokens per block (pass1)
#define THREADS 256

// ---------------------------------------------------------------------------
// Pass 1: fp32 GEMM + sigmoid/L1/bias + wave-parallel routing + margin gate.
// Thread layout: tx = tid&15 (expert lane), ty = tid>>4 (token group).
// Each thread: 8 tokens (t = t0+ty+16i) x 16 experts (e = tx+16j).
// Group of expert e = e>>5 = j>>1  (since tx<16).
// ---------------------------------------------------------------------------
__global__ __launch_bounds__(THREADS, 1) void router_pass1(
    const float* __restrict__ x, const float* __restrict__ w1,
    const float* __restrict__ b_lin, const float* __restrict__ bias,
    float* __restrict__ out_vals, float* __restrict__ out_idx,
    int* __restrict__ wsI)
{
    __shared__ float4 ws[8][NE];   // [chunk][expert^chunk], 32 KB

    const int tid = threadIdx.x;
    const int tx  = tid & 15;
    const int ty  = tid >> 4;
    const int t0  = blockIdx.x * BT;

    const float4* x4 = (const float4*)x;   // x[t][k] -> x4[t*512 + k/4]
    const float4* w4 = (const float4*)w1;  // w1[e][k] -> w4[e*512 + k/4]

    // staging identity for this thread: 8 (e,c) pairs
    int se[8], scn[8];
#pragma unroll
    for (int p = 0; p < 8; ++p) {
        const int id = tid + 256 * p;
        se[p]  = id >> 3;
        scn[p] = id & 7;
    }

    float acc[8][16];
#pragma unroll
    for (int i = 0; i < 8; ++i)
#pragma unroll
        for (int j = 0; j < 16; ++j) acc[i][j] = 0.0f;

    int xbase[8];
#pragma unroll
    for (int i = 0; i < 8; ++i) xbase[i] = (t0 + ty + 16 * i) * 512;

    // prologue: stage tile 0
    {
        float4 wreg[8];
#pragma unroll
        for (int p = 0; p < 8; ++p) wreg[p] = w4[se[p] * 512 + scn[p]];
#pragma unroll
        for (int p = 0; p < 8; ++p) ws[scn[p]][se[p] ^ scn[p]] = wreg[p];
    }
    __syncthreads();

    for (int tile = 0; tile < DIM / 32; ++tile) {
        const int kq0 = tile * 8;
        // prefetch next tile's w into registers (latency hidden under fma)
        float4 wreg[8];
        if (tile < DIM / 32 - 1) {
#pragma unroll
            for (int p = 0; p < 8; ++p)
                wreg[p] = w4[se[p] * 512 + kq0 + 8 + scn[p]];
        }
#pragma unroll 2
        for (int c = 0; c < 8; ++c) {
            float4 xv[8];
#pragma unroll
            for (int i = 0; i < 8; ++i) xv[i] = x4[xbase[i] + kq0 + c];
#pragma unroll
            for (int jh = 0; jh < 2; ++jh) {
                float4 wv[8];
#pragma unroll
                for (int jj = 0; jj < 8; ++jj)
                    wv[jj] = ws[c][(tx + 16 * (jh * 8 + jj)) ^ c];
#pragma unroll
                for (int i = 0; i < 8; ++i)
#pragma unroll
                    for (int jj = 0; jj < 8; ++jj) {
                        float& A = acc[i][jh * 8 + jj];
                        A = fmaf(xv[i].x, wv[jj].x, A);
                        A = fmaf(xv[i].y, wv[jj].y, A);
                        A = fmaf(xv[i].z, wv[jj].z, A);
                        A = fmaf(xv[i].w, wv[jj].w, A);
                    }
            }
        }
        __syncthreads();
        if (tile < DIM / 32 - 1) {
#pragma unroll
            for (int p = 0; p < 8; ++p) ws[scn[p]][se[p] ^ scn[p]] = wreg[p];
        }
        __syncthreads();
    }

    // per-lane expert biases
    float bl[16], bs[16];
#pragma unroll
    for (int j = 0; j < 16; ++j) {
        bl[j] = b_lin[tx + 16 * j];
        bs[j] = bias[tx + 16 * j];
    }

#pragma unroll
    for (int i = 0; i < 8; ++i) {
        // ---- sigmoid + L1 normalize + bias ----
        float s16[16];
        float psum = 0.0f;
#pragma unroll
        for (int j = 0; j < 16; ++j) {
            const float l = acc[i][j] + bl[j];
            const float s = 1.0f / (1.0f + expf(-l));
            s16[j] = s;
            psum += s;
        }
#pragma unroll
        for (int m = 1; m <= 8; m <<= 1) psum += __shfl_xor(psum, m);
#pragma unroll
        for (int j = 0; j < 16; ++j) s16[j] = s16[j] / psum + bs[j];

        // ---- group maxes (group g <-> j in {2g, 2g+1}) ----
        float gm[8];
#pragma unroll
        for (int g = 0; g < 8; ++g) gm[g] = fmaxf(s16[2 * g], s16[2 * g + 1]);
#pragma unroll
        for (int m = 1; m <= 8; m <<= 1)
#pragma unroll
            for (int g = 0; g < 8; ++g) gm[g] = fmaxf(gm[g], __shfl_xor(gm[g], m));

        // ---- top-4 groups (strict >, ascending g => lower idx wins ties) ----
        unsigned keep = 0u;
        float g4v = 0.0f, g5v = 0.0f;
#pragma unroll
        for (int r = 0; r < 5; ++r) {
            float bv = -1e30f; int bg = 0;
#pragma unroll
            for (int g = 0; g < 8; ++g)
                if (!((keep >> g) & 1) && gm[g] > bv) { bv = gm[g]; bg = g; }
            if (r < 4) { keep |= 1u << bg; g4v = bv; }
            else g5v = bv;
        }
        const float gapA = g4v - g5v;

        // ---- top-8 experts + 9th for the last gap ----
        unsigned avail = 0u;
#pragma unroll
        for (int j = 0; j < 16; ++j)
            if ((keep >> (j >> 1)) & 1) avail |= 1u << j;
        float tv[9]; int te[9];
#pragma unroll
        for (int r = 0; r < 9; ++r) {
            float bv = -1e30f; int bj = -1;
#pragma unroll
            for (int j = 0; j < 16; ++j)
                if ((avail >> j) & 1) {
                    const float v = s16[j];
                    if (v > bv) { bv = v; bj = j; }
                }
            int be = (bj < 0) ? 10000 : (tx + 16 * bj);
#pragma unroll
            for (int m = 1; m <= 8; m <<= 1) {
                const float ov = __shfl_xor(bv, m);
                const int   oe = __shfl_xor(be, m);
                if (ov > bv || (ov == bv && oe < be)) { bv = ov; be = oe; }
            }
            tv[r] = bv; te[r] = be;
            if (r < 8 && be < NE && (be & 15) == tx) avail &= ~(1u << (be >> 4));
        }

        float margin = gapA;
#pragma unroll
        for (int r = 0; r < 8; ++r) margin = fminf(margin, tv[r] - tv[r + 1]);

        if (tx == 0) {
            const int t = t0 + ty + 16 * i;
            const int base = t * TOPK;
#pragma unroll
            for (int r = 0; r < 8; ++r) {
                out_vals[base + r] = tv[r] * RSCALE;
                out_idx[base + r]  = (float)te[r];
            }
            if (margin < TAU) {
                const int slot = atomicAdd(&wsI[0], 1);
                if (slot < NTOK) wsI[4 + slot] = t;
            }
        }
    }
}

// ---------------------------------------------------------------------------
// Pass 2: exact fp64 recompute + reroute for margin-flagged tokens.
// One block per flagged token (grid-stride). 256 threads = 256 experts.
// ---------------------------------------------------------------------------
__global__ __launch_bounds__(THREADS, 1) void router_pass2(
    const float* __restrict__ x, const float* __restrict__ w1,
    const float* __restrict__ b_lin, const float* __restrict__ bias,
    float* __restrict__ out_vals, float* __restrict__ out_idx,
    const int* __restrict__ wsI)
{
    __shared__ double xrow[DIM];
    __shared__ double red[256];
    __shared__ double sc[NE];

    const int tid = threadIdx.x;
    const int count = min(wsI[0], NTOK);
    const int* list = wsI + 4;
    const float4* x4 = (const float4*)x;
    const float4* w4 = (const float4*)w1;

    for (int li = blockIdx.x; li < count; li += gridDim.x) {
        const int t = list[li];
        __syncthreads();   // previous iteration fully done before xrow reuse
#pragma unroll
        for (int q = 0; q < 2; ++q) {
            const int id = tid + 256 * q;
            const float4 v = x4[t * 512 + id];
            xrow[id * 4 + 0] = (double)v.x;
            xrow[id * 4 + 1] = (double)v.y;
            xrow[id * 4 + 2] = (double)v.z;
            xrow[id * 4 + 3] = (double)v.w;
        }
        __syncthreads();

        const int e = tid;
        double a = 0.0;
#pragma unroll 4
        for (int k4 = 0; k4 < 512; ++k4) {
            const float4 wv = w4[e * 512 + k4];
            a = fma(xrow[k4 * 4 + 0], (double)wv.x, a);
            a = fma(xrow[k4 * 4 + 1], (double)wv.y, a);
            a = fma(xrow[k4 * 4 + 2], (double)wv.z, a);
            a = fma(xrow[k4 * 4 + 3], (double)wv.w, a);
        }
        const double l = a + (double)b_lin[e];
        const double s = 1.0 / (1.0 + exp(-l));
        red[tid] = s;
        __syncthreads();
        for (int off = 128; off > 0; off >>= 1) {
            if (tid < off) red[tid] += red[tid + off];
            __syncthreads();
        }
        const double psum = red[0];
        sc[e] = s / psum + (double)bias[e];
        __syncthreads();

        if (tid == 0) {
            double gmax[NG];
            for (int g = 0; g < NG; ++g) {
                double m = -INFINITY;
                for (int q = 0; q < GSZ; ++q) {
                    const double v = sc[g * GSZ + q];
                    m = (v > m) ? v : m;
                }
                gmax[g] = m;
            }
            unsigned keep = 0u;
            for (int r = 0; r < NLIM; ++r) {
                int best = 0; double bv = -INFINITY;
                for (int g = 0; g < NG; ++g) {
                    if (keep & (1u << g)) continue;
                    if (gmax[g] > bv) { bv = gmax[g]; best = g; }
                }
                keep |= 1u << best;
            }
            double tv[TOPK]; int ti[TOPK];
            for (int r = 0; r < TOPK; ++r) { tv[r] = -INFINITY; ti[r] = NE; }
            for (int g = 0; g < NG; ++g) {
                if (!(keep & (1u << g))) continue;
                for (int q = 0; q < GSZ; ++q) {
                    const int ee = g * GSZ + q;
                    const double v = sc[ee];
                    if (v > tv[TOPK - 1]) {
                        int p = TOPK - 1;
                        while (p > 0 && v > tv[p - 1]) {
                            tv[p] = tv[p - 1]; ti[p] = ti[p - 1]; --p;
                        }
                        tv[p] = v; ti[p] = ee;
                    }
                }
            }
            const int base = t * TOPK;
            for (int r = 0; r < TOPK; ++r) {
                out_vals[base + r] = (float)(tv[r] * (double)RSCALE);
                out_idx[base + r]  = (float)ti[r];
            }
        }
    }
}

extern "C" void kernel_launch(void* const* d_in, const int* in_sizes, int n_in,
                              void* d_out, int out_size, void* d_ws, size_t ws_size,
                              hipStream_t stream) {
    const float* x     = (const float*)d_in[0];
    const float* w1    = (const float*)d_in[1];
    const float* b_lin = (const float*)d_in[2];
    const float* bias  = (const float*)d_in[3];
    float* out_vals = (float*)d_out;
    float* out_idx  = (float*)d_out + (size_t)NTOK * TOPK;

    hipMemsetAsync(d_ws, 0, 16, stream);
    router_pass1<<<dim3(NTOK / BT), THREADS, 0, stream>>>(
        x, w1, b_lin, bias, out_vals, out_idx, (int*)d_ws);
    router_pass2<<<dim3(256), THREADS, 0, stream>>>(
        x, w1, b_lin, bias, out_vals, out_idx, (const int*)d_ws);
}

// Round 3
// 587.556 us; speedup vs baseline: 1.9481x; 1.9481x over previous
//
#include <hip/hip_runtime.h>
#include <math.h>

#define NTOK   32768
#define DIM    2048
#define NE     256
#define NG     8
#define GSZ    32
#define NLIM   4
#define TOPK   8
#define RSCALE 2.5f
#define TAU    4e-7f

#define BT      64            // tokens per block (pass1)
#define THREADS 256
#define NTILE   (DIM / 32)    // 64 k-tiles of 32 (= 8 float4 chunks)

typedef const __attribute__((address_space(1))) void GASV;
typedef __attribute__((address_space(3))) void LASV;

__device__ __forceinline__ void gload16(const void* g, void* l) {
    __builtin_amdgcn_global_load_lds((GASV*)g, (LASV*)l, 16, 0, 0);
}

// ---------------------------------------------------------------------------
// Pass 1: fp32 GEMM (global_load_lds dbuf) + sigmoid/L1/bias + wave-parallel
// routing + margin gate. tx=tid&31 expert lane (e=tx+32j, group=j),
// ty=tid>>5 token group (t = t0 + ty*8 + i, i<8). acc[8 tok][8 exp] fp32.
// ---------------------------------------------------------------------------
__global__ __launch_bounds__(THREADS, 2) void router_pass1(
    const float* __restrict__ x, const float* __restrict__ w1,
    const float* __restrict__ b_lin, const float* __restrict__ bias,
    float* __restrict__ out_vals, float* __restrict__ out_idx,
    int* __restrict__ wsI)
{
    // ws: [expert][chunk ^ (e&7)] float4 ; xs: [token][chunk] float4
    __shared__ float4 wsA[2048], wsB[2048], xsA[512], xsB[512];   // 80 KB

    const int tid  = threadIdx.x;
    const int tx   = tid & 31;
    const int ty   = tid >> 5;
    const int wave = tid >> 6;
    const int lane = tid & 63;
    const int t0   = blockIdx.x * BT;

    const float4* x4 = (const float4*)x;   // x[t][k]  -> x4[t*512 + k/4]
    const float4* w4 = (const float4*)w1;  // w1[e][k] -> w4[e*512 + k/4]

    // async stage of one 32-k tile into (wsb, xsb); k40 = tile*8 (float4 units)
    auto STAGE = [&](float4* wsb, float4* xsb, int k40) {
#pragma unroll
        for (int q = 0; q < 8; ++q) {               // w: 256 e x 8 chunks
            const int chunk = wave * 8 + q;
            const int id = chunk * 64 + lane;
            const int e = id >> 3, cs = id & 7;
            const int c = cs ^ (e & 7);             // pre-swizzled source
            gload16(&w4[e * 512 + k40 + c], &wsb[chunk * 64]);
        }
#pragma unroll
        for (int q = 0; q < 2; ++q) {               // x: 64 t x 8 chunks
            const int chunk = wave * 2 + q;
            const int id = chunk * 64 + lane;
            const int tkn = id >> 3, cs = id & 7;
            gload16(&x4[(t0 + tkn) * 512 + k40 + cs], &xsb[chunk * 64]);
        }
    };

    float acc[8][8];
#pragma unroll
    for (int i = 0; i < 8; ++i)
#pragma unroll
        for (int j = 0; j < 8; ++j) acc[i][j] = 0.0f;

    const int cxor = tx & 7;
    int wso[8], xso[8];
#pragma unroll
    for (int j = 0; j < 8; ++j) wso[j] = (tx + 32 * j) * 8;
#pragma unroll
    for (int i = 0; i < 8; ++i) xso[i] = (ty * 8 + i) * 8;

    STAGE(wsA, xsA, 0);
    asm volatile("s_waitcnt vmcnt(0)" ::: "memory");
    __syncthreads();

    for (int tile = 0; tile < NTILE; ++tile) {
        const float4* wsb = (tile & 1) ? wsB : wsA;
        const float4* xsb = (tile & 1) ? xsB : xsA;
        if (tile < NTILE - 1)
            STAGE((tile & 1) ? wsA : wsB, (tile & 1) ? xsA : xsB,
                  (tile + 1) * 8);

        for (int c = 0; c < 8; ++c) {
            float4 xv[8];
#pragma unroll
            for (int i = 0; i < 8; ++i) xv[i] = xsb[xso[i] + c];
            const int cs = c ^ cxor;
#pragma unroll
            for (int j = 0; j < 8; ++j) {
                const float4 wv = wsb[wso[j] + cs];
#pragma unroll
                for (int i = 0; i < 8; ++i) {
                    float& A = acc[i][j];
                    A = fmaf(xv[i].x, wv.x, A);
                    A = fmaf(xv[i].y, wv.y, A);
                    A = fmaf(xv[i].z, wv.z, A);
                    A = fmaf(xv[i].w, wv.w, A);
                }
            }
        }
        asm volatile("s_waitcnt vmcnt(0)" ::: "memory");
        __syncthreads();
    }

    // ---- epilogue: per-lane biases for experts e = tx + 32j ----
    float bl[8], bs[8];
#pragma unroll
    for (int j = 0; j < 8; ++j) {
        bl[j] = b_lin[tx + 32 * j];
        bs[j] = bias[tx + 32 * j];
    }

#pragma unroll
    for (int i = 0; i < 8; ++i) {
        float s8[8];
        float psum = 0.0f;
#pragma unroll
        for (int j = 0; j < 8; ++j) {
            const float l = acc[i][j] + bl[j];
            const float s = 1.0f / (1.0f + expf(-l));
            s8[j] = s;
            psum += s;
        }
#pragma unroll
        for (int m = 1; m <= 16; m <<= 1) psum += __shfl_xor(psum, m);
#pragma unroll
        for (int j = 0; j < 8; ++j) s8[j] = s8[j] / psum + bs[j];

        // group maxes: group j's 32 experts live across the 32 tx lanes
        float gm[8];
#pragma unroll
        for (int j = 0; j < 8; ++j) gm[j] = s8[j];
#pragma unroll
        for (int m = 1; m <= 16; m <<= 1)
#pragma unroll
            for (int j = 0; j < 8; ++j)
                gm[j] = fmaxf(gm[j], __shfl_xor(gm[j], m));

        // top-4 groups (strict >, ascending scan -> lower idx wins ties)
        unsigned keep = 0u;
        float g4v = 0.0f, g5v = 0.0f;
#pragma unroll
        for (int r = 0; r < 5; ++r) {
            float bv = -1e30f; int bg = 0;
#pragma unroll
            for (int g = 0; g < 8; ++g)
                if (!((keep >> g) & 1) && gm[g] > bv) { bv = gm[g]; bg = g; }
            if (r < 4) { keep |= 1u << bg; g4v = bv; }
            else g5v = bv;
        }
        float margin = g4v - g5v;

        // mask out non-kept groups
#pragma unroll
        for (int j = 0; j < 8; ++j)
            if (!((keep >> j) & 1)) s8[j] = -1e30f;

        // top-8 experts (+9th for gap): 9 rounds of cross-lane argmax
        float tv[9]; int te[9];
#pragma unroll
        for (int r = 0; r < 9; ++r) {
            float bv = -1e30f; int bj = 8;
#pragma unroll
            for (int j = 0; j < 8; ++j)
                if (s8[j] > bv) { bv = s8[j]; bj = j; }
            int be = (bj < 8) ? (tx + 32 * bj) : 9999;
#pragma unroll
            for (int m = 1; m <= 16; m <<= 1) {
                const float ov = __shfl_xor(bv, m);
                const int   oe = __shfl_xor(be, m);
                if (ov > bv || (ov == bv && oe < be)) { bv = ov; be = oe; }
            }
            tv[r] = bv; te[r] = be;
            if (r < 8 && (be & 31) == tx) s8[be >> 5] = -1e30f;  // consume
        }
#pragma unroll
        for (int r = 0; r < 8; ++r) margin = fminf(margin, tv[r] - tv[r + 1]);

        if (tx == 0) {
            const int t = t0 + ty * 8 + i;
            const int base = t * TOPK;
#pragma unroll
            for (int r = 0; r < 8; ++r) {
                out_vals[base + r] = tv[r] * RSCALE;
                out_idx[base + r]  = (float)te[r];
            }
            if (margin < TAU) {
                const int slot = atomicAdd(&wsI[0], 1);
                if (slot < NTOK) wsI[4 + slot] = t;
            }
        }
    }
}

// ---------------------------------------------------------------------------
// Pass 2: exact fp64 recompute + reroute for margin-flagged tokens.
// ---------------------------------------------------------------------------
__global__ __launch_bounds__(THREADS, 1) void router_pass2(
    const float* __restrict__ x, const float* __restrict__ w1,
    const float* __restrict__ b_lin, const float* __restrict__ bias,
    float* __restrict__ out_vals, float* __restrict__ out_idx,
    const int* __restrict__ wsI)
{
    __shared__ double xrow[DIM];
    __shared__ double red[256];
    __shared__ double sc[NE];

    const int tid = threadIdx.x;
    const int count = min(wsI[0], NTOK);
    const int* list = wsI + 4;
    const float4* x4 = (const float4*)x;
    const float4* w4 = (const float4*)w1;

    for (int li = blockIdx.x; li < count; li += gridDim.x) {
        const int t = list[li];
        __syncthreads();
#pragma unroll
        for (int q = 0; q < 2; ++q) {
            const int id = tid + 256 * q;
            const float4 v = x4[t * 512 + id];
            xrow[id * 4 + 0] = (double)v.x;
            xrow[id * 4 + 1] = (double)v.y;
            xrow[id * 4 + 2] = (double)v.z;
            xrow[id * 4 + 3] = (double)v.w;
        }
        __syncthreads();

        const int e = tid;
        double a = 0.0;
#pragma unroll 4
        for (int k4 = 0; k4 < 512; ++k4) {
            const float4 wv = w4[e * 512 + k4];
            a = fma(xrow[k4 * 4 + 0], (double)wv.x, a);
            a = fma(xrow[k4 * 4 + 1], (double)wv.y, a);
            a = fma(xrow[k4 * 4 + 2], (double)wv.z, a);
            a = fma(xrow[k4 * 4 + 3], (double)wv.w, a);
        }
        const double l = a + (double)b_lin[e];
        const double s = 1.0 / (1.0 + exp(-l));
        red[tid] = s;
        __syncthreads();
        for (int off = 128; off > 0; off >>= 1) {
            if (tid < off) red[tid] += red[tid + off];
            __syncthreads();
        }
        sc[e] = s / red[0] + (double)bias[e];
        __syncthreads();

        if (tid == 0) {
            double gmax[NG];
            for (int g = 0; g < NG; ++g) {
                double m = -INFINITY;
                for (int q = 0; q < GSZ; ++q) {
                    const double v = sc[g * GSZ + q];
                    m = (v > m) ? v : m;
                }
                gmax[g] = m;
            }
            unsigned keep = 0u;
            for (int r = 0; r < NLIM; ++r) {
                int best = 0; double bv = -INFINITY;
                for (int g = 0; g < NG; ++g) {
                    if (keep & (1u << g)) continue;
                    if (gmax[g] > bv) { bv = gmax[g]; best = g; }
                }
                keep |= 1u << best;
            }
            double tv[TOPK]; int ti[TOPK];
            for (int r = 0; r < TOPK; ++r) { tv[r] = -INFINITY; ti[r] = NE; }
            for (int g = 0; g < NG; ++g) {
                if (!(keep & (1u << g))) continue;
                for (int q = 0; q < GSZ; ++q) {
                    const int ee = g * GSZ + q;
                    const double v = sc[ee];
                    if (v > tv[TOPK - 1]) {
                        int p = TOPK - 1;
                        while (p > 0 && v > tv[p - 1]) {
                            tv[p] = tv[p - 1]; ti[p] = ti[p - 1]; --p;
                        }
                        tv[p] = v; ti[p] = ee;
                    }
                }
            }
            const int base = t * TOPK;
            for (int r = 0; r < TOPK; ++r) {
                out_vals[base + r] = (float)(tv[r] * (double)RSCALE);
                out_idx[base + r]  = (float)ti[r];
            }
        }
    }
}

extern "C" void kernel_launch(void* const* d_in, const int* in_sizes, int n_in,
                              void* d_out, int out_size, void* d_ws, size_t ws_size,
                              hipStream_t stream) {
    const float* x     = (const float*)d_in[0];
    const float* w1    = (const float*)d_in[1];
    const float* b_lin = (const float*)d_in[2];
    const float* bias  = (const float*)d_in[3];
    float* out_vals = (float*)d_out;
    float* out_idx  = (float*)d_out + (size_t)NTOK * TOPK;

    hipMemsetAsync(d_ws, 0, 16, stream);
    router_pass1<<<dim3(NTOK / BT), THREADS, 0, stream>>>(
        x, w1, b_lin, bias, out_vals, out_idx, (int*)d_ws);
    router_pass2<<<dim3(256), THREADS, 0, stream>>>(
        x, w1, b_lin, bias, out_vals, out_idx, (const int*)d_ws);
}

// Round 4
// 347.661 us; speedup vs baseline: 3.2923x; 1.6900x over previous
//
#include <hip/hip_runtime.h>
#include <math.h>

#define NTOK   32768
#define DIM    2048
#define NE     256
#define NG     8
#define GSZ    32
#define NLIM   4
#define TOPK   8
#define RSCALE 2.5f
#define TAU    4e-7f

#define BT      64            // tokens per block (pass1)
#define THREADS 256
#define KT      16
#define NKT     (DIM / KT)    // 128 k-tiles
#define WOFF    262144        // byte offset of w-split tiles inside d_ws

typedef __bf16 bf16x8 __attribute__((ext_vector_type(8)));
typedef float  f32x16 __attribute__((ext_vector_type(16)));

typedef const __attribute__((address_space(1))) void GASV;
typedef __attribute__((address_space(3))) void LASV;

__device__ __forceinline__ void gload16(const void* g, void* l) {
    __builtin_amdgcn_global_load_lds((GASV*)g, (LASV*)l, 16, 0, 0);
}
// bijective XOR swizzle within each 1 KB block of a 32 B-row tile
__device__ __forceinline__ int swzf(int b) { return b ^ (((b >> 7) & 7) << 4); }

// 3-way exact bf16 split (truncation): v = h + m + l to 2^-24 rel
__device__ __forceinline__ void split3(float v, unsigned short& h,
                                       unsigned short& m, unsigned short& l) {
    unsigned int uh = __float_as_uint(v);
    float fh = __uint_as_float(uh & 0xFFFF0000u);
    float rm = v - fh;
    unsigned int um = __float_as_uint(rm);
    float fm = __uint_as_float(um & 0xFFFF0000u);
    float rl = rm - fm;
    h = (unsigned short)(uh >> 16);
    m = (unsigned short)(um >> 16);
    l = (unsigned short)(__float_as_uint(rl) >> 16);
}

// ---------------------------------------------------------------------------
// Prekernel: split w1 into 3 bf16 planes, stored tile-swizzled fragment-linear
// so pass1 can stage them with linear global_load_lds.
// Layout: wt[s][kt][slot] (16 B cells); cell at LDS byte b=slot*16 holds
// (e = u>>5, kb = (u>>4)&1) with u = swzf(b): 8 bf16 of w1[e][kt*16+kb*8 ..].
// ---------------------------------------------------------------------------
__global__ __launch_bounds__(256) void wsplit_kernel(
    const float* __restrict__ w1, unsigned short* __restrict__ wt)
{
    const int g = blockIdx.x * 256 + threadIdx.x;    // [0, 3*128*512)
    const int s    = g >> 16;
    const int rem  = g & 65535;
    const int kt   = rem >> 9;
    const int slot = rem & 511;
    const int u  = swzf(slot * 16);
    const int e  = u >> 5;
    const int kb = (u >> 4) & 1;
    const float* src = w1 + (size_t)e * DIM + kt * 16 + kb * 8;

    uint4 o;
    unsigned int w[4];
#pragma unroll
    for (int q = 0; q < 4; ++q) {
        unsigned short hs[2];
#pragma unroll
        for (int z = 0; z < 2; ++z) {
            unsigned short h, m, l;
            split3(src[q * 2 + z], h, m, l);
            hs[z] = (s == 0) ? h : ((s == 1) ? m : l);
        }
        w[q] = (unsigned int)hs[0] | ((unsigned int)hs[1] << 16);
    }
    o.x = w[0]; o.y = w[1]; o.z = w[2]; o.w = w[3];
    *(uint4*)(wt + (size_t)g * 8) = o;
}

// ---------------------------------------------------------------------------
// Pass 1: 3-way-split bf16 MFMA GEMM (6 passes, fp32 accum) + routing + gate.
// Block: 64 tokens x 256 experts, 4 waves (wm=wave>>1 token-half,
// wn=wave&1 expert-half). Wave tile: 32 tok x 128 exp = 4 n-tiles of 32x32.
// ---------------------------------------------------------------------------
__global__ __launch_bounds__(THREADS, 2) void router_pass1(
    const float* __restrict__ x, const unsigned short* __restrict__ wt,
    const float* __restrict__ b_lin, const float* __restrict__ bias,
    float* __restrict__ out_vals, float* __restrict__ out_idx,
    int* __restrict__ wsI)
{
    __shared__ union {
        struct {
            unsigned short A[2 * 3 * 1024];   // [c][s] 64x16 bf16 tiles
            unsigned short B[2 * 3 * 4096];   // [c][s] 256x16 bf16 tiles
        } t;
        float sc[64 * 260];                   // raw logits
    } sm;

    const int tid  = threadIdx.x;
    const int lane = tid & 63;
    const int wave = tid >> 6;
    const int l31  = lane & 31;
    const int hi   = lane >> 5;
    const int wm   = wave >> 1;
    const int wn   = wave & 1;
    const int t0   = blockIdx.x * BT;

    // frag-read LDS byte offsets (tile-local, swizzled)
    const int a_off = swzf((32 * wm + l31) * 32 + hi * 16);
    int b_off[4];
#pragma unroll
    for (int j = 0; j < 4; ++j)
        b_off[j] = swzf((wn * 128 + j * 32 + l31) * 32 + hi * 16);

    // x staging identity: row = tid>>2 (token), kq = tid&3 (float4 within k16)
    const int xrow = tid >> 2, xkq = tid & 3;
    const float* xgp = x + (size_t)(t0 + xrow) * DIM + xkq * 4;
    const int xw_off = swzf(xrow * 32 + xkq * 8);

    f32x16 acc[4] = {};

    auto ABASE = [&](int c, int s) -> char* {
        return (char*)(sm.t.A + (c * 3 + s) * 1024);
    };
    auto BBASE = [&](int c, int s) -> char* {
        return (char*)(sm.t.B + (c * 3 + s) * 4096);
    };

    // stage B-split tiles for k-tile kt into buffer c (6 gload16 per thread)
    auto STAGE_B = [&](int c, int kt) {
#pragma unroll
        for (int p = 0; p < 6; ++p) {
            const int s = p >> 1;
            const int sb = (p & 1) * 256 + wave * 64;       // slot base (wave-uniform)
            gload16(wt + ((size_t)s * 65536 + (size_t)kt * 512 + sb + lane) * 8,
                    BBASE(c, s) + sb * 16);
        }
    };
    // convert x float4 -> 3 splits, write into buffer c
    auto WRITE_X = [&](int c, float4 v) {
        unsigned short h[4], m[4], l[4];
        split3(v.x, h[0], m[0], l[0]);
        split3(v.y, h[1], m[1], l[1]);
        split3(v.z, h[2], m[2], l[2]);
        split3(v.w, h[3], m[3], l[3]);
        uint2 ph, pm, pl;
        ph.x = h[0] | ((unsigned)h[1] << 16); ph.y = h[2] | ((unsigned)h[3] << 16);
        pm.x = m[0] | ((unsigned)m[1] << 16); pm.y = m[2] | ((unsigned)m[3] << 16);
        pl.x = l[0] | ((unsigned)l[1] << 16); pl.y = l[2] | ((unsigned)l[3] << 16);
        *(uint2*)(ABASE(c, 0) + xw_off) = ph;
        *(uint2*)(ABASE(c, 1) + xw_off) = pm;
        *(uint2*)(ABASE(c, 2) + xw_off) = pl;
    };

    // prologue: stage tile 0
    STAGE_B(0, 0);
    WRITE_X(0, *(const float4*)xgp);
    asm volatile("s_waitcnt vmcnt(0)" ::: "memory");
    __syncthreads();

    for (int kt = 0; kt < NKT; ++kt) {
        const int c = kt & 1;
        float4 xf;
        if (kt < NKT - 1) {
            STAGE_B(c ^ 1, kt + 1);
            xf = *(const float4*)(xgp + (kt + 1) * KT);
        }
        // compute tile kt from buffer c
        bf16x8 a0 = *(const bf16x8*)(ABASE(c, 0) + a_off);
        bf16x8 a1 = *(const bf16x8*)(ABASE(c, 1) + a_off);
        bf16x8 a2 = *(const bf16x8*)(ABASE(c, 2) + a_off);
#pragma unroll
        for (int j = 0; j < 4; ++j) {
            bf16x8 bh = *(const bf16x8*)(BBASE(c, 0) + b_off[j]);
            bf16x8 bm = *(const bf16x8*)(BBASE(c, 1) + b_off[j]);
            bf16x8 bl = *(const bf16x8*)(BBASE(c, 2) + b_off[j]);
            acc[j] = __builtin_amdgcn_mfma_f32_32x32x16_bf16(a0, bh, acc[j], 0, 0, 0);
            acc[j] = __builtin_amdgcn_mfma_f32_32x32x16_bf16(a0, bm, acc[j], 0, 0, 0);
            acc[j] = __builtin_amdgcn_mfma_f32_32x32x16_bf16(a1, bh, acc[j], 0, 0, 0);
            acc[j] = __builtin_amdgcn_mfma_f32_32x32x16_bf16(a0, bl, acc[j], 0, 0, 0);
            acc[j] = __builtin_amdgcn_mfma_f32_32x32x16_bf16(a1, bm, acc[j], 0, 0, 0);
            acc[j] = __builtin_amdgcn_mfma_f32_32x32x16_bf16(a2, bh, acc[j], 0, 0, 0);
        }
        if (kt < NKT - 1) WRITE_X(c ^ 1, xf);
        __syncthreads();
    }

    // ---- write raw logits to LDS (C layout: col=lane&31, row=(r&3)+8*(r>>2)+4*hi)
#pragma unroll
    for (int j = 0; j < 4; ++j) {
#pragma unroll
        for (int r = 0; r < 16; ++r) {
            const int tok = 32 * wm + (r & 3) + 8 * (r >> 2) + 4 * hi;
            const int e   = wn * 128 + j * 32 + l31;
            sm.sc[tok * 260 + e] = acc[j][r];
        }
    }
    __syncthreads();

    // ---- routing (round-3 verified epilogue), tx = expert lane, ty = token grp
    const int tx = tid & 31;
    const int ty = tid >> 5;
    float blv[8], bsv[8];
#pragma unroll
    for (int j = 0; j < 8; ++j) {
        blv[j] = b_lin[tx + 32 * j];
        bsv[j] = bias[tx + 32 * j];
    }

#pragma unroll
    for (int i = 0; i < 8; ++i) {
        float s8[8];
        float psum = 0.0f;
#pragma unroll
        for (int j = 0; j < 8; ++j) {
            const float lg = sm.sc[(ty * 8 + i) * 260 + tx + 32 * j] + blv[j];
            const float s = 1.0f / (1.0f + expf(-lg));
            s8[j] = s;
            psum += s;
        }
#pragma unroll
        for (int m = 1; m <= 16; m <<= 1) psum += __shfl_xor(psum, m);
#pragma unroll
        for (int j = 0; j < 8; ++j) s8[j] = s8[j] / psum + bsv[j];

        float gm[8];
#pragma unroll
        for (int j = 0; j < 8; ++j) gm[j] = s8[j];
#pragma unroll
        for (int m = 1; m <= 16; m <<= 1)
#pragma unroll
            for (int j = 0; j < 8; ++j)
                gm[j] = fmaxf(gm[j], __shfl_xor(gm[j], m));

        unsigned keep = 0u;
        float g4v = 0.0f, g5v = 0.0f;
#pragma unroll
        for (int r = 0; r < 5; ++r) {
            float bv = -1e30f; int bg = 0;
#pragma unroll
            for (int g = 0; g < 8; ++g)
                if (!((keep >> g) & 1) && gm[g] > bv) { bv = gm[g]; bg = g; }
            if (r < 4) { keep |= 1u << bg; g4v = bv; }
            else g5v = bv;
        }
        float margin = g4v - g5v;

#pragma unroll
        for (int j = 0; j < 8; ++j)
            if (!((keep >> j) & 1)) s8[j] = -1e30f;

        float tv[9]; int te[9];
#pragma unroll
        for (int r = 0; r < 9; ++r) {
            float bv = -1e30f; int bj = 8;
#pragma unroll
            for (int j = 0; j < 8; ++j)
                if (s8[j] > bv) { bv = s8[j]; bj = j; }
            int be = (bj < 8) ? (tx + 32 * bj) : 9999;
#pragma unroll
            for (int m = 1; m <= 16; m <<= 1) {
                const float ov = __shfl_xor(bv, m);
                const int   oe = __shfl_xor(be, m);
                if (ov > bv || (ov == bv && oe < be)) { bv = ov; be = oe; }
            }
            tv[r] = bv; te[r] = be;
            if (r < 8 && (be & 31) == tx) s8[be >> 5] = -1e30f;
        }
#pragma unroll
        for (int r = 0; r < 8; ++r) margin = fminf(margin, tv[r] - tv[r + 1]);

        if (tx == 0) {
            const int t = t0 + ty * 8 + i;
            const int base = t * TOPK;
#pragma unroll
            for (int r = 0; r < 8; ++r) {
                out_vals[base + r] = tv[r] * RSCALE;
                out_idx[base + r]  = (float)te[r];
            }
            if (margin < TAU) {
                const int slot = atomicAdd(&wsI[0], 1);
                if (slot < NTOK) wsI[4 + slot] = t;
            }
        }
    }
}

// ---------------------------------------------------------------------------
// Pass 2: exact fp64 recompute + reroute for margin-flagged tokens.
// ---------------------------------------------------------------------------
__global__ __launch_bounds__(THREADS, 1) void router_pass2(
    const float* __restrict__ x, const float* __restrict__ w1,
    const float* __restrict__ b_lin, const float* __restrict__ bias,
    float* __restrict__ out_vals, float* __restrict__ out_idx,
    const int* __restrict__ wsI)
{
    __shared__ double xrow[DIM];
    __shared__ double red[256];
    __shared__ double sc[NE];

    const int tid = threadIdx.x;
    const int count = min(wsI[0], NTOK);
    const int* list = wsI + 4;
    const float4* x4 = (const float4*)x;
    const float4* w4 = (const float4*)w1;

    for (int li = blockIdx.x; li < count; li += gridDim.x) {
        const int t = list[li];
        __syncthreads();
#pragma unroll
        for (int q = 0; q < 2; ++q) {
            const int id = tid + 256 * q;
            const float4 v = x4[t * 512 + id];
            xrow[id * 4 + 0] = (double)v.x;
            xrow[id * 4 + 1] = (double)v.y;
            xrow[id * 4 + 2] = (double)v.z;
            xrow[id * 4 + 3] = (double)v.w;
        }
        __syncthreads();

        const int e = tid;
        double a = 0.0;
#pragma unroll 4
        for (int k4 = 0; k4 < 512; ++k4) {
            const float4 wv = w4[e * 512 + k4];
            a = fma(xrow[k4 * 4 + 0], (double)wv.x, a);
            a = fma(xrow[k4 * 4 + 1], (double)wv.y, a);
            a = fma(xrow[k4 * 4 + 2], (double)wv.z, a);
            a = fma(xrow[k4 * 4 + 3], (double)wv.w, a);
        }
        const double lg = a + (double)b_lin[e];
        const double s = 1.0 / (1.0 + exp(-lg));
        red[tid] = s;
        __syncthreads();
        for (int off = 128; off > 0; off >>= 1) {
            if (tid < off) red[tid] += red[tid + off];
            __syncthreads();
        }
        sc[e] = s / red[0] + (double)bias[e];
        __syncthreads();

        if (tid == 0) {
            double gmax[NG];
            for (int g = 0; g < NG; ++g) {
                double mx = -INFINITY;
                for (int q = 0; q < GSZ; ++q) {
                    const double v = sc[g * GSZ + q];
                    mx = (v > mx) ? v : mx;
                }
                gmax[g] = mx;
            }
            unsigned keep = 0u;
            for (int r = 0; r < NLIM; ++r) {
                int best = 0; double bv = -INFINITY;
                for (int g = 0; g < NG; ++g) {
                    if (keep & (1u << g)) continue;
                    if (gmax[g] > bv) { bv = gmax[g]; best = g; }
                }
                keep |= 1u << best;
            }
            double tv[TOPK]; int ti[TOPK];
            for (int r = 0; r < TOPK; ++r) { tv[r] = -INFINITY; ti[r] = NE; }
            for (int g = 0; g < NG; ++g) {
                if (!(keep & (1u << g))) continue;
                for (int q = 0; q < GSZ; ++q) {
                    const int ee = g * GSZ + q;
                    const double v = sc[ee];
                    if (v > tv[TOPK - 1]) {
                        int p = TOPK - 1;
                        while (p > 0 && v > tv[p - 1]) {
                            tv[p] = tv[p - 1]; ti[p] = ti[p - 1]; --p;
                        }
                        tv[p] = v; ti[p] = ee;
                    }
                }
            }
            const int base = t * TOPK;
            for (int r = 0; r < TOPK; ++r) {
                out_vals[base + r] = (float)(tv[r] * (double)RSCALE);
                out_idx[base + r]  = (float)ti[r];
            }
        }
    }
}

extern "C" void kernel_launch(void* const* d_in, const int* in_sizes, int n_in,
                              void* d_out, int out_size, void* d_ws, size_t ws_size,
                              hipStream_t stream) {
    const float* x     = (const float*)d_in[0];
    const float* w1    = (const float*)d_in[1];
    const float* b_lin = (const float*)d_in[2];
    const float* bias  = (const float*)d_in[3];
    float* out_vals = (float*)d_out;
    float* out_idx  = (float*)d_out + (size_t)NTOK * TOPK;

    int* wsI = (int*)d_ws;
    unsigned short* wt = (unsigned short*)((char*)d_ws + WOFF);

    hipMemsetAsync(d_ws, 0, 16, stream);
    wsplit_kernel<<<dim3(768), 256, 0, stream>>>(w1, wt);
    router_pass1<<<dim3(NTOK / BT), THREADS, 0, stream>>>(
        x, wt, b_lin, bias, out_vals, out_idx, wsI);
    router_pass2<<<dim3(256), THREADS, 0, stream>>>(
        x, w1, b_lin, bias, out_vals, out_idx, (const int*)d_ws);
}

// Round 5
// 270.955 us; speedup vs baseline: 4.2243x; 1.2831x over previous
//
#include <hip/hip_runtime.h>
#include <math.h>

#define NTOK   32768
#define DIM    2048
#define NE     256
#define NG     8
#define GSZ    32
#define NLIM   4
#define TOPK   8
#define RSCALE 2.5f
#define TAU    4e-7f

#define BT      64
#define THREADS 256
#define KT      16
#define NKT     (DIM / KT)        // 128
#define WOFF    262144            // wt at d_ws + 256 KB (list below)
#define TILE_B  16384             // one staged B tile: [plane][khalf][256e] * 16B

typedef __bf16 bf16x8 __attribute__((ext_vector_type(8)));
typedef float  f32x16 __attribute__((ext_vector_type(16)));

typedef const __attribute__((address_space(1))) void GASV;
typedef __attribute__((address_space(3))) void LASV;

__device__ __forceinline__ void gload16(const void* g, void* l) {
    __builtin_amdgcn_global_load_lds((GASV*)g, (LASV*)l, 16, 0, 0);
}

// 2-plane truncation split of 8 f32 -> h-plane bf16x8 + r-plane bf16x8
__device__ __forceinline__ void split_pack(float4 a, float4 b,
                                           bf16x8& h8, bf16x8& r8) {
    float v[8] = {a.x, a.y, a.z, a.w, b.x, b.y, b.z, b.w};
    union { unsigned int u[4]; bf16x8 v8; } H, R;
#pragma unroll
    for (int q = 0; q < 4; ++q) {
        const unsigned int u0 = __float_as_uint(v[2 * q]);
        const unsigned int u1 = __float_as_uint(v[2 * q + 1]);
        H.u[q] = (u0 >> 16) | (u1 & 0xFFFF0000u);
        const float r0 = v[2 * q]     - __uint_as_float(u0 & 0xFFFF0000u);
        const float r1 = v[2 * q + 1] - __uint_as_float(u1 & 0xFFFF0000u);
        R.u[q] = (__float_as_uint(r0) >> 16) |
                 (__float_as_uint(r1) & 0xFFFF0000u);
    }
    h8 = H.v8; r8 = R.v8;
}

// ---------------------------------------------------------------------------
// Prekernel: split w1 into 2 bf16 planes, layout wt[kt][plane][khalf][e]:
// 16B cell g = ((kt*2+p)*2+hi)*256+e holds w1[e][kt*16+hi*8 .. +8), plane p.
// ---------------------------------------------------------------------------
__global__ __launch_bounds__(256) void wsplit_kernel(
    const float* __restrict__ w1, unsigned int* __restrict__ wt)
{
    const int g  = blockIdx.x * 256 + threadIdx.x;    // [0, 131072)
    const int e  = g & 255;
    const int hi = (g >> 8) & 1;
    const int p  = (g >> 9) & 1;
    const int kt = g >> 10;
    const float* src = w1 + (size_t)e * DIM + kt * 16 + hi * 8;

    uint4 o;
    unsigned int w[4];
#pragma unroll
    for (int q = 0; q < 4; ++q) {
        const float v0 = src[2 * q], v1 = src[2 * q + 1];
        const unsigned int u0 = __float_as_uint(v0);
        const unsigned int u1 = __float_as_uint(v1);
        if (p == 0) {
            w[q] = (u0 >> 16) | (u1 & 0xFFFF0000u);
        } else {
            const float r0 = v0 - __uint_as_float(u0 & 0xFFFF0000u);
            const float r1 = v1 - __uint_as_float(u1 & 0xFFFF0000u);
            w[q] = (__float_as_uint(r0) >> 16) |
                   (__float_as_uint(r1) & 0xFFFF0000u);
        }
    }
    o.x = w[0]; o.y = w[1]; o.z = w[2]; o.w = w[3];
    *(uint4*)(wt + (size_t)g * 4) = o;
}

// ---------------------------------------------------------------------------
// Pass 1: 2-plane / 3-pass bf16 MFMA GEMM, counted-vmcnt 3-buffer pipeline,
// A built in registers from global x. Block: 64 tok x 256 exp, 4 waves.
// ---------------------------------------------------------------------------
__global__ __launch_bounds__(THREADS, 3) void router_pass1(
    const float* __restrict__ x, const unsigned int* __restrict__ wt,
    const float* __restrict__ b_lin, const float* __restrict__ bias,
    float* __restrict__ out_vals, float* __restrict__ out_idx,
    int* __restrict__ wsI)
{
    __shared__ union {
        char  B[3 * TILE_B];      // 48 KB: 3 staged tiles
        float sc[32 * 260];       // 33.3 KB: logits for a 32-token half
    } sm;

    const int tid  = threadIdx.x;
    const int lane = tid & 63;
    const int wave = tid >> 6;
    const int l31  = lane & 31;
    const int hi   = lane >> 5;
    const int wm   = wave >> 1;
    const int wn   = wave & 1;
    const int t0   = blockIdx.x * BT;

    // per-lane x row pointer: row = t0 + wm*32 + l31, k-half = hi
    const float4* xrow =
        (const float4*)(x + (size_t)(t0 + wm * 32 + l31) * DIM) + hi * 2;

    const char* wsrc = (const char*)wt;

    char* p_cur = sm.B;
    char* p_nxt = sm.B + TILE_B;
    char* p_stg = sm.B + 2 * TILE_B;

    // stage one 16 KB B tile (linear copy, 4 gload16/thread)
    auto STAGE = [&](char* ldsbase, int kt) {
#pragma unroll
        for (int q = 0; q < 4; ++q) {
            const int chunk = wave * 4 + q;
            gload16(wsrc + (size_t)kt * TILE_B + chunk * 1024 + lane * 16,
                    ldsbase + chunk * 1024);
        }
    };

    f32x16 acc[4] = {};

    // prologue: stage tiles 0,1 first, THEN x(0) (ordering matters for vmcnt)
    STAGE(p_cur, 0);
    STAGE(p_nxt, 1);
    asm volatile("" ::: "memory");
    float4 f0 = xrow[0];
    float4 f1 = xrow[1];

    const int e_base = (wn * 128 + l31) * 16;
    const int hi4k   = hi * 4096;

    for (int kt = 0; kt < NKT; ++kt) {
        if (kt + 1 < NKT) asm volatile("s_waitcnt vmcnt(6)" ::: "memory");
        else              asm volatile("s_waitcnt vmcnt(2)" ::: "memory");
        asm volatile("s_barrier" ::: "memory");

        float4 nf0, nf1;
        if (kt + 1 < NKT) {
            nf0 = xrow[(kt + 1) * 4];
            nf1 = xrow[(kt + 1) * 4 + 1];
        }

        bf16x8 ah, ar;
        split_pack(f0, f1, ah, ar);

#pragma unroll
        for (int j = 0; j < 4; ++j) {
            const int eo = e_base + j * 512;
            bf16x8 bh = *(const bf16x8*)(p_cur + hi4k + eo);
            bf16x8 br = *(const bf16x8*)(p_cur + 8192 + hi4k + eo);
            acc[j] = __builtin_amdgcn_mfma_f32_32x32x16_bf16(ah, bh, acc[j], 0, 0, 0);
            acc[j] = __builtin_amdgcn_mfma_f32_32x32x16_bf16(ah, br, acc[j], 0, 0, 0);
            acc[j] = __builtin_amdgcn_mfma_f32_32x32x16_bf16(ar, bh, acc[j], 0, 0, 0);
        }

        if (kt + 2 < NKT) STAGE(p_stg, kt + 2);

        f0 = nf0; f1 = nf1;
        char* t = p_cur; p_cur = p_nxt; p_nxt = p_stg; p_stg = t;
    }

    __syncthreads();   // pipeline done; LDS reused as sc

    // ---- routing epilogue, two halves of 32 tokens ----
    const int tx = tid & 31;
    const int ty = tid >> 5;
    float blv[8], bsv[8];
#pragma unroll
    for (int j = 0; j < 8; ++j) {
        blv[j] = b_lin[tx + 32 * j];
        bsv[j] = bias[tx + 32 * j];
    }

    for (int h = 0; h < 2; ++h) {
        if (h) __syncthreads();
        if (wm == h) {
#pragma unroll
            for (int j = 0; j < 4; ++j) {
#pragma unroll
                for (int r = 0; r < 16; ++r) {
                    const int row = (r & 3) + 8 * (r >> 2) + 4 * hi;
                    const int e   = wn * 128 + j * 32 + l31;
                    sm.sc[row * 260 + e] = acc[j][r];
                }
            }
        }
        __syncthreads();

#pragma unroll
        for (int i = 0; i < 4; ++i) {
            const int row = ty * 4 + i;
            float s8[8];
            float psum = 0.0f;
#pragma unroll
            for (int j = 0; j < 8; ++j) {
                const float lg = sm.sc[row * 260 + tx + 32 * j] + blv[j];
                const float s = 1.0f / (1.0f + expf(-lg));
                s8[j] = s;
                psum += s;
            }
#pragma unroll
            for (int m = 1; m <= 16; m <<= 1) psum += __shfl_xor(psum, m);
#pragma unroll
            for (int j = 0; j < 8; ++j) s8[j] = s8[j] / psum + bsv[j];

            float gm[8];
#pragma unroll
            for (int j = 0; j < 8; ++j) gm[j] = s8[j];
#pragma unroll
            for (int m = 1; m <= 16; m <<= 1)
#pragma unroll
                for (int j = 0; j < 8; ++j)
                    gm[j] = fmaxf(gm[j], __shfl_xor(gm[j], m));

            unsigned keep = 0u;
            float g4v = 0.0f, g5v = 0.0f;
#pragma unroll
            for (int r = 0; r < 5; ++r) {
                float bv = -1e30f; int bg = 0;
#pragma unroll
                for (int g = 0; g < 8; ++g)
                    if (!((keep >> g) & 1) && gm[g] > bv) { bv = gm[g]; bg = g; }
                if (r < 4) { keep |= 1u << bg; g4v = bv; }
                else g5v = bv;
            }
            float margin = g4v - g5v;

#pragma unroll
            for (int j = 0; j < 8; ++j)
                if (!((keep >> j) & 1)) s8[j] = -1e30f;

            float tv[9]; int te[9];
#pragma unroll
            for (int r = 0; r < 9; ++r) {
                float bv = -1e30f; int bj = 8;
#pragma unroll
                for (int j = 0; j < 8; ++j)
                    if (s8[j] > bv) { bv = s8[j]; bj = j; }
                int be = (bj < 8) ? (tx + 32 * bj) : 9999;
#pragma unroll
                for (int m = 1; m <= 16; m <<= 1) {
                    const float ov = __shfl_xor(bv, m);
                    const int   oe = __shfl_xor(be, m);
                    if (ov > bv || (ov == bv && oe < be)) { bv = ov; be = oe; }
                }
                tv[r] = bv; te[r] = be;
                if (r < 8 && (be & 31) == tx) s8[be >> 5] = -1e30f;
            }
#pragma unroll
            for (int r = 0; r < 8; ++r) margin = fminf(margin, tv[r] - tv[r + 1]);

            if (tx == 0) {
                const int t = t0 + h * 32 + row;
                const int base = t * TOPK;
#pragma unroll
                for (int r = 0; r < 8; ++r) {
                    out_vals[base + r] = tv[r] * RSCALE;
                    out_idx[base + r]  = (float)te[r];
                }
                if (margin < TAU) {
                    const int slot = atomicAdd(&wsI[0], 1);
                    if (slot < 60000) wsI[4 + slot] = t;
                }
            }
        }
    }
}

// ---------------------------------------------------------------------------
// Pass 2: exact fp64 recompute + reroute for margin-flagged tokens.
// ---------------------------------------------------------------------------
__global__ __launch_bounds__(THREADS, 1) void router_pass2(
    const float* __restrict__ x, const float* __restrict__ w1,
    const float* __restrict__ b_lin, const float* __restrict__ bias,
    float* __restrict__ out_vals, float* __restrict__ out_idx,
    const int* __restrict__ wsI)
{
    __shared__ double xrow[DIM];
    __shared__ double red[256];
    __shared__ double sc[NE];

    const int tid = threadIdx.x;
    const int count = min(wsI[0], 60000);
    const int* list = wsI + 4;
    const float4* x4 = (const float4*)x;
    const float4* w4 = (const float4*)w1;

    for (int li = blockIdx.x; li < count; li += gridDim.x) {
        const int t = list[li];
        __syncthreads();
#pragma unroll
        for (int q = 0; q < 2; ++q) {
            const int id = tid + 256 * q;
            const float4 v = x4[t * 512 + id];
            xrow[id * 4 + 0] = (double)v.x;
            xrow[id * 4 + 1] = (double)v.y;
            xrow[id * 4 + 2] = (double)v.z;
            xrow[id * 4 + 3] = (double)v.w;
        }
        __syncthreads();

        const int e = tid;
        double a0 = 0.0, a1 = 0.0, a2 = 0.0, a3 = 0.0;
#pragma unroll 2
        for (int k4 = 0; k4 < 512; k4 += 4) {
#pragma unroll
            for (int z = 0; z < 4; ++z) {
                const float4 wv = w4[e * 512 + k4 + z];
                double* ac = (z == 0) ? &a0 : (z == 1) ? &a1 : (z == 2) ? &a2 : &a3;
                *ac = fma(xrow[(k4 + z) * 4 + 0], (double)wv.x, *ac);
                *ac = fma(xrow[(k4 + z) * 4 + 1], (double)wv.y, *ac);
                *ac = fma(xrow[(k4 + z) * 4 + 2], (double)wv.z, *ac);
                *ac = fma(xrow[(k4 + z) * 4 + 3], (double)wv.w, *ac);
            }
        }
        const double lg = ((a0 + a1) + (a2 + a3)) + (double)b_lin[e];
        const double s = 1.0 / (1.0 + exp(-lg));
        red[tid] = s;
        __syncthreads();
        for (int off = 128; off > 0; off >>= 1) {
            if (tid < off) red[tid] += red[tid + off];
            __syncthreads();
        }
        sc[e] = s / red[0] + (double)bias[e];
        __syncthreads();

        if (tid == 0) {
            double gmax[NG];
            for (int g = 0; g < NG; ++g) {
                double mx = -INFINITY;
                for (int q = 0; q < GSZ; ++q) {
                    const double v = sc[g * GSZ + q];
                    mx = (v > mx) ? v : mx;
                }
                gmax[g] = mx;
            }
            unsigned keep = 0u;
            for (int r = 0; r < NLIM; ++r) {
                int best = 0; double bv = -INFINITY;
                for (int g = 0; g < NG; ++g) {
                    if (keep & (1u << g)) continue;
                    if (gmax[g] > bv) { bv = gmax[g]; best = g; }
                }
                keep |= 1u << best;
            }
            double tv[TOPK]; int ti[TOPK];
            for (int r = 0; r < TOPK; ++r) { tv[r] = -INFINITY; ti[r] = NE; }
            for (int g = 0; g < NG; ++g) {
                if (!(keep & (1u << g))) continue;
                for (int q = 0; q < GSZ; ++q) {
                    const int ee = g * GSZ + q;
                    const double v = sc[ee];
                    if (v > tv[TOPK - 1]) {
                        int p = TOPK - 1;
                        while (p > 0 && v > tv[p - 1]) {
                            tv[p] = tv[p - 1]; ti[p] = ti[p - 1]; --p;
                        }
                        tv[p] = v; ti[p] = ee;
                    }
                }
            }
            const int base = t * TOPK;
            for (int r = 0; r < TOPK; ++r) {
                out_vals[base + r] = (float)(tv[r] * (double)RSCALE);
                out_idx[base + r]  = (float)ti[r];
            }
        }
    }
}

extern "C" void kernel_launch(void* const* d_in, const int* in_sizes, int n_in,
                              void* d_out, int out_size, void* d_ws, size_t ws_size,
                              hipStream_t stream) {
    const float* x     = (const float*)d_in[0];
    const float* w1    = (const float*)d_in[1];
    const float* b_lin = (const float*)d_in[2];
    const float* bias  = (const float*)d_in[3];
    float* out_vals = (float*)d_out;
    float* out_idx  = (float*)d_out + (size_t)NTOK * TOPK;

    int* wsI = (int*)d_ws;
    unsigned int* wt = (unsigned int*)((char*)d_ws + WOFF);

    hipMemsetAsync(d_ws, 0, 16, stream);
    wsplit_kernel<<<dim3(512), 256, 0, stream>>>(w1, wt);
    router_pass1<<<dim3(NTOK / BT), THREADS, 0, stream>>>(
        x, wt, b_lin, bias, out_vals, out_idx, wsI);
    router_pass2<<<dim3(256), THREADS, 0, stream>>>(
        x, w1, b_lin, bias, out_vals, out_idx, (const int*)d_ws);
}

// Round 6
// 268.432 us; speedup vs baseline: 4.2640x; 1.0094x over previous
//
#include <hip/hip_runtime.h>
#include <math.h>

#define NTOK   32768
#define DIM    2048
#define NE     256
#define NG     8
#define GSZ    32
#define NLIM   4
#define TOPK   8
#define RSCALE 2.5f
#define TAU    4e-7f

#define BT      64
#define THREADS 256
#define KT      16
#define NKT     (DIM / KT)        // 128
#define WOFF    262144            // wt at d_ws + 256 KB
#define TILE_B  16384             // one staged B tile: [plane][khalf][256e] * 16B

typedef __bf16 bf16x8 __attribute__((ext_vector_type(8)));
typedef float  f32x16 __attribute__((ext_vector_type(16)));

typedef const __attribute__((address_space(1))) void GASV;
typedef __attribute__((address_space(3))) void LASV;

__device__ __forceinline__ void gload16(const void* g, void* l) {
    __builtin_amdgcn_global_load_lds((GASV*)g, (LASV*)l, 16, 0, 0);
}

// 2-plane truncation split of 8 f32 -> h-plane bf16x8 + r-plane bf16x8
__device__ __forceinline__ void split_pack(float4 a, float4 b,
                                           bf16x8& h8, bf16x8& r8) {
    float v[8] = {a.x, a.y, a.z, a.w, b.x, b.y, b.z, b.w};
    union { unsigned int u[4]; bf16x8 v8; } H, R;
#pragma unroll
    for (int q = 0; q < 4; ++q) {
        const unsigned int u0 = __float_as_uint(v[2 * q]);
        const unsigned int u1 = __float_as_uint(v[2 * q + 1]);
        H.u[q] = (u0 >> 16) | (u1 & 0xFFFF0000u);
        const float r0 = v[2 * q]     - __uint_as_float(u0 & 0xFFFF0000u);
        const float r1 = v[2 * q + 1] - __uint_as_float(u1 & 0xFFFF0000u);
        R.u[q] = (__float_as_uint(r0) >> 16) |
                 (__float_as_uint(r1) & 0xFFFF0000u);
    }
    h8 = H.v8; r8 = R.v8;
}

// ---------------------------------------------------------------------------
// Prekernel: split w1 into 2 bf16 planes, layout wt[kt][plane][khalf][e]:
// 16B cell g = ((kt*2+p)*2+hi)*256+e holds w1[e][kt*16+hi*8 .. +8), plane p.
// ---------------------------------------------------------------------------
__global__ __launch_bounds__(256) void wsplit_kernel(
    const float* __restrict__ w1, unsigned int* __restrict__ wt)
{
    const int g  = blockIdx.x * 256 + threadIdx.x;    // [0, 131072)
    const int e  = g & 255;
    const int hi = (g >> 8) & 1;
    const int p  = (g >> 9) & 1;
    const int kt = g >> 10;
    const float* src = w1 + (size_t)e * DIM + kt * 16 + hi * 8;

    uint4 o;
    unsigned int w[4];
#pragma unroll
    for (int q = 0; q < 4; ++q) {
        const float v0 = src[2 * q], v1 = src[2 * q + 1];
        const unsigned int u0 = __float_as_uint(v0);
        const unsigned int u1 = __float_as_uint(v1);
        if (p == 0) {
            w[q] = (u0 >> 16) | (u1 & 0xFFFF0000u);
        } else {
            const float r0 = v0 - __uint_as_float(u0 & 0xFFFF0000u);
            const float r1 = v1 - __uint_as_float(u1 & 0xFFFF0000u);
            w[q] = (__float_as_uint(r0) >> 16) |
                   (__float_as_uint(r1) & 0xFFFF0000u);
        }
    }
    o.x = w[0]; o.y = w[1]; o.z = w[2]; o.w = w[3];
    *(uint4*)(wt + (size_t)g * 4) = o;
}

// ---------------------------------------------------------------------------
// Pass 1: 2-plane / 3-pass bf16 MFMA GEMM. Counted-vmcnt 3-buffer pipeline
// with clean asm (NO memory clobber), raw s_barrier, sched_barrier pins.
// Steady-state VMEM queue: [X(kt)x2, S(kt)x4, X(kt+1)x2, S(kt+1)x4] = 12;
// vmcnt(6) at iter top retires exactly group kt. x loaded 2 tiles ahead.
// ---------------------------------------------------------------------------
__global__ __launch_bounds__(THREADS, 3) void router_pass1(
    const float* __restrict__ x, const unsigned int* __restrict__ wt,
    const float* __restrict__ b_lin, const float* __restrict__ bias,
    float* __restrict__ out_vals, float* __restrict__ out_idx,
    int* __restrict__ wsI)
{
    __shared__ union {
        alignas(16) char B[3 * TILE_B];   // 48 KB: 3 staged tiles
        float sc[32 * 260];               // 33.3 KB: logits for a 32-tok half
    } sm;

    const int tid  = threadIdx.x;
    const int lane = tid & 63;
    const int wave = tid >> 6;
    const int l31  = lane & 31;
    const int hi   = lane >> 5;
    const int wm   = wave >> 1;
    const int wn   = wave & 1;
    const int t0   = blockIdx.x * BT;

    // per-lane x row pointer: row = t0 + wm*32 + l31, k-half = hi
    const float4* xrow =
        (const float4*)(x + (size_t)(t0 + wm * 32 + l31) * DIM) + hi * 2;

    const char* wsrc = (const char*)wt;

    char* p_cur = sm.B;
    char* p_nxt = sm.B + TILE_B;
    char* p_stg = sm.B + 2 * TILE_B;

    auto STAGE = [&](char* ldsbase, int kt) {
#pragma unroll
        for (int q = 0; q < 4; ++q) {
            const int chunk = wave * 4 + q;
            gload16(wsrc + (size_t)kt * TILE_B + chunk * 1024 + lane * 16,
                    ldsbase + chunk * 1024);
        }
    };

    f32x16 acc[4] = {};

    // prologue: X0, S0, X1, S1 (group order fixed for exact vmcnt counting)
    float4 xa0 = xrow[0], xa1 = xrow[1];
    __builtin_amdgcn_sched_barrier(0);
    STAGE(p_cur, 0);
    __builtin_amdgcn_sched_barrier(0);
    float4 xb0 = xrow[4], xb1 = xrow[5];
    __builtin_amdgcn_sched_barrier(0);
    STAGE(p_nxt, 1);
    __builtin_amdgcn_sched_barrier(0);

    const int e_base = (wn * 128 + l31) * 16;
    const int hi4k   = hi * 4096;

    for (int kt = 0; kt < NKT; ++kt) {
        if (kt < NKT - 1) asm volatile("s_waitcnt vmcnt(6)");
        else              asm volatile("s_waitcnt vmcnt(0)");
        __builtin_amdgcn_sched_barrier(0);
        __builtin_amdgcn_s_barrier();
        __builtin_amdgcn_sched_barrier(0);

        float4 xc0, xc1;
        if (kt + 2 < NKT) {
            xc0 = xrow[(kt + 2) * 4];
            xc1 = xrow[(kt + 2) * 4 + 1];
            __builtin_amdgcn_sched_barrier(0);
            STAGE(p_stg, kt + 2);
            __builtin_amdgcn_sched_barrier(0);
        }

        bf16x8 ah, ar;
        split_pack(xa0, xa1, ah, ar);

        __builtin_amdgcn_s_setprio(1);
#pragma unroll
        for (int j = 0; j < 4; ++j) {
            const int eo = e_base + j * 512;
            bf16x8 bh = *(const bf16x8*)(p_cur + hi4k + eo);
            bf16x8 br = *(const bf16x8*)(p_cur + 8192 + hi4k + eo);
            acc[j] = __builtin_amdgcn_mfma_f32_32x32x16_bf16(ah, bh, acc[j], 0, 0, 0);
            acc[j] = __builtin_amdgcn_mfma_f32_32x32x16_bf16(ah, br, acc[j], 0, 0, 0);
            acc[j] = __builtin_amdgcn_mfma_f32_32x32x16_bf16(ar, bh, acc[j], 0, 0, 0);
        }
        __builtin_amdgcn_s_setprio(0);

        xa0 = xb0; xa1 = xb1; xb0 = xc0; xb1 = xc1;
        char* t = p_cur; p_cur = p_nxt; p_nxt = p_stg; p_stg = t;
    }

    __syncthreads();   // full drain once; LDS reused as sc

    // ---- routing epilogue, two halves of 32 tokens ----
    const int tx = tid & 31;
    const int ty = tid >> 5;
    float blv[8], bsv[8];
#pragma unroll
    for (int j = 0; j < 8; ++j) {
        blv[j] = b_lin[tx + 32 * j];
        bsv[j] = bias[tx + 32 * j];
    }

    for (int h = 0; h < 2; ++h) {
        if (h) __syncthreads();
        if (wm == h) {
#pragma unroll
            for (int j = 0; j < 4; ++j) {
#pragma unroll
                for (int r = 0; r < 16; ++r) {
                    const int row = (r & 3) + 8 * (r >> 2) + 4 * hi;
                    const int e   = wn * 128 + j * 32 + l31;
                    sm.sc[row * 260 + e] = acc[j][r];
                }
            }
        }
        __syncthreads();

#pragma unroll
        for (int i = 0; i < 4; ++i) {
            const int row = ty * 4 + i;
            float s8[8];
            float psum = 0.0f;
#pragma unroll
            for (int j = 0; j < 8; ++j) {
                const float lg = sm.sc[row * 260 + tx + 32 * j] + blv[j];
                const float s = 1.0f / (1.0f + expf(-lg));
                s8[j] = s;
                psum += s;
            }
#pragma unroll
            for (int m = 1; m <= 16; m <<= 1) psum += __shfl_xor(psum, m);
#pragma unroll
            for (int j = 0; j < 8; ++j) s8[j] = s8[j] / psum + bsv[j];

            float gm[8];
#pragma unroll
            for (int j = 0; j < 8; ++j) gm[j] = s8[j];
#pragma unroll
            for (int m = 1; m <= 16; m <<= 1)
#pragma unroll
                for (int j = 0; j < 8; ++j)
                    gm[j] = fmaxf(gm[j], __shfl_xor(gm[j], m));

            unsigned keep = 0u;
            float g4v = 0.0f, g5v = 0.0f;
#pragma unroll
            for (int r = 0; r < 5; ++r) {
                float bv = -1e30f; int bg = 0;
#pragma unroll
                for (int g = 0; g < 8; ++g)
                    if (!((keep >> g) & 1) && gm[g] > bv) { bv = gm[g]; bg = g; }
                if (r < 4) { keep |= 1u << bg; g4v = bv; }
                else g5v = bv;
            }
            float margin = g4v - g5v;

#pragma unroll
            for (int j = 0; j < 8; ++j)
                if (!((keep >> j) & 1)) s8[j] = -1e30f;

            float tv[9]; int te[9];
#pragma unroll
            for (int r = 0; r < 9; ++r) {
                float bv = -1e30f; int bj = 8;
#pragma unroll
                for (int j = 0; j < 8; ++j)
                    if (s8[j] > bv) { bv = s8[j]; bj = j; }
                int be = (bj < 8) ? (tx + 32 * bj) : 9999;
#pragma unroll
                for (int m = 1; m <= 16; m <<= 1) {
                    const float ov = __shfl_xor(bv, m);
                    const int   oe = __shfl_xor(be, m);
                    if (ov > bv || (ov == bv && oe < be)) { bv = ov; be = oe; }
                }
                tv[r] = bv; te[r] = be;
                if (r < 8 && (be & 31) == tx) s8[be >> 5] = -1e30f;
            }
#pragma unroll
            for (int r = 0; r < 8; ++r) margin = fminf(margin, tv[r] - tv[r + 1]);

            if (tx == 0) {
                const int t = t0 + h * 32 + row;
                const int base = t * TOPK;
#pragma unroll
                for (int r = 0; r < 8; ++r) {
                    out_vals[base + r] = tv[r] * RSCALE;
                    out_idx[base + r]  = (float)te[r];
                }
                if (margin < TAU) {
                    const int slot = atomicAdd(&wsI[0], 1);
                    if (slot < 60000) wsI[4 + slot] = t;
                }
            }
        }
    }
}

// ---------------------------------------------------------------------------
// Pass 2: exact fp64 recompute + reroute for margin-flagged tokens.
// ---------------------------------------------------------------------------
__global__ __launch_bounds__(THREADS, 1) void router_pass2(
    const float* __restrict__ x, const float* __restrict__ w1,
    const float* __restrict__ b_lin, const float* __restrict__ bias,
    float* __restrict__ out_vals, float* __restrict__ out_idx,
    const int* __restrict__ wsI)
{
    __shared__ double xrow[DIM];
    __shared__ double red[256];
    __shared__ double sc[NE];

    const int tid = threadIdx.x;
    const int count = min(wsI[0], 60000);
    const int* list = wsI + 4;
    const float4* x4 = (const float4*)x;
    const float4* w4 = (const float4*)w1;

    for (int li = blockIdx.x; li < count; li += gridDim.x) {
        const int t = list[li];
        __syncthreads();
#pragma unroll
        for (int q = 0; q < 2; ++q) {
            const int id = tid + 256 * q;
            const float4 v = x4[t * 512 + id];
            xrow[id * 4 + 0] = (double)v.x;
            xrow[id * 4 + 1] = (double)v.y;
            xrow[id * 4 + 2] = (double)v.z;
            xrow[id * 4 + 3] = (double)v.w;
        }
        __syncthreads();

        const int e = tid;
        double a0 = 0.0, a1 = 0.0, a2 = 0.0, a3 = 0.0;
#pragma unroll 2
        for (int k4 = 0; k4 < 512; k4 += 4) {
#pragma unroll
            for (int z = 0; z < 4; ++z) {
                const float4 wv = w4[e * 512 + k4 + z];
                double* ac = (z == 0) ? &a0 : (z == 1) ? &a1 : (z == 2) ? &a2 : &a3;
                *ac = fma(xrow[(k4 + z) * 4 + 0], (double)wv.x, *ac);
                *ac = fma(xrow[(k4 + z) * 4 + 1], (double)wv.y, *ac);
                *ac = fma(xrow[(k4 + z) * 4 + 2], (double)wv.z, *ac);
                *ac = fma(xrow[(k4 + z) * 4 + 3], (double)wv.w, *ac);
            }
        }
        const double lg = ((a0 + a1) + (a2 + a3)) + (double)b_lin[e];
        const double s = 1.0 / (1.0 + exp(-lg));
        red[tid] = s;
        __syncthreads();
        for (int off = 128; off > 0; off >>= 1) {
            if (tid < off) red[tid] += red[tid + off];
            __syncthreads();
        }
        sc[e] = s / red[0] + (double)bias[e];
        __syncthreads();

        if (tid == 0) {
            double gmax[NG];
            for (int g = 0; g < NG; ++g) {
                double mx = -INFINITY;
                for (int q = 0; q < GSZ; ++q) {
                    const double v = sc[g * GSZ + q];
                    mx = (v > mx) ? v : mx;
                }
                gmax[g] = mx;
            }
            unsigned keep = 0u;
            for (int r = 0; r < NLIM; ++r) {
                int best = 0; double bv = -INFINITY;
                for (int g = 0; g < NG; ++g) {
                    if (keep & (1u << g)) continue;
                    if (gmax[g] > bv) { bv = gmax[g]; best = g; }
                }
                keep |= 1u << best;
            }
            double tv[TOPK]; int ti[TOPK];
            for (int r = 0; r < TOPK; ++r) { tv[r] = -INFINITY; ti[r] = NE; }
            for (int g = 0; g < NG; ++g) {
                if (!(keep & (1u << g))) continue;
                for (int q = 0; q < GSZ; ++q) {
                    const int ee = g * GSZ + q;
                    const double v = sc[ee];
                    if (v > tv[TOPK - 1]) {
                        int p = TOPK - 1;
                        while (p > 0 && v > tv[p - 1]) {
                            tv[p] = tv[p - 1]; ti[p] = ti[p - 1]; --p;
                        }
                        tv[p] = v; ti[p] = ee;
                    }
                }
            }
            const int base = t * TOPK;
            for (int r = 0; r < TOPK; ++r) {
                out_vals[base + r] = (float)(tv[r] * (double)RSCALE);
                out_idx[base + r]  = (float)ti[r];
            }
        }
    }
}

extern "C" void kernel_launch(void* const* d_in, const int* in_sizes, int n_in,
                              void* d_out, int out_size, void* d_ws, size_t ws_size,
                              hipStream_t stream) {
    const float* x     = (const float*)d_in[0];
    const float* w1    = (const float*)d_in[1];
    const float* b_lin = (const float*)d_in[2];
    const float* bias  = (const float*)d_in[3];
    float* out_vals = (float*)d_out;
    float* out_idx  = (float*)d_out + (size_t)NTOK * TOPK;

    int* wsI = (int*)d_ws;
    unsigned int* wt = (unsigned int*)((char*)d_ws + WOFF);

    hipMemsetAsync(d_ws, 0, 16, stream);
    wsplit_kernel<<<dim3(512), 256, 0, stream>>>(w1, wt);
    router_pass1<<<dim3(NTOK / BT), THREADS, 0, stream>>>(
        x, wt, b_lin, bias, out_vals, out_idx, wsI);
    router_pass2<<<dim3(256), THREADS, 0, stream>>>(
        x, w1, b_lin, bias, out_vals, out_idx, (const int*)d_ws);
}

// Round 7
// 261.154 us; speedup vs baseline: 4.3828x; 1.0279x over previous
//
#include <hip/hip_runtime.h>
#include <math.h>

#define NTOK   32768
#define DIM    2048
#define NE     256
#define NG     8
#define GSZ    32
#define NLIM   4
#define TOPK   8
#define RSCALE 2.5f
#define TAU    4e-7f

#define BT      64
#define THREADS 256
#define KT      16
#define NKT     (DIM / KT)        // 128
#define WOFF    262144            // wt at d_ws + 256 KB
#define TILE_B  16384             // one staged B tile: [plane][khalf][256e] * 16B

typedef __bf16 bf16x8 __attribute__((ext_vector_type(8)));
typedef float  f32x16 __attribute__((ext_vector_type(16)));

typedef const __attribute__((address_space(1))) void GASV;
typedef __attribute__((address_space(3))) void LASV;

__device__ __forceinline__ void gload16(const void* g, void* l) {
    __builtin_amdgcn_global_load_lds((GASV*)g, (LASV*)l, 16, 0, 0);
}

// ---------------------------------------------------------------------------
// Prekernel: split w1 into 2 bf16 planes, layout wt[kt][plane][khalf][e]:
// 16B cell g = ((kt*2+p)*2+hi)*256+e holds w1[e][kt*16+hi*8 .. +8), plane p.
// ---------------------------------------------------------------------------
__global__ __launch_bounds__(256) void wsplit_kernel(
    const float* __restrict__ w1, unsigned int* __restrict__ wt)
{
    const int g  = blockIdx.x * 256 + threadIdx.x;    // [0, 131072)
    const int e  = g & 255;
    const int hi = (g >> 8) & 1;
    const int p  = (g >> 9) & 1;
    const int kt = g >> 10;
    const float* src = w1 + (size_t)e * DIM + kt * 16 + hi * 8;

    uint4 o;
    unsigned int w[4];
#pragma unroll
    for (int q = 0; q < 4; ++q) {
        const float v0 = src[2 * q], v1 = src[2 * q + 1];
        const unsigned int u0 = __float_as_uint(v0);
        const unsigned int u1 = __float_as_uint(v1);
        if (p == 0) {
            w[q] = (u0 >> 16) | (u1 & 0xFFFF0000u);
        } else {
            const float r0 = v0 - __uint_as_float(u0 & 0xFFFF0000u);
            const float r1 = v1 - __uint_as_float(u1 & 0xFFFF0000u);
            w[q] = (__float_as_uint(r0) >> 16) |
                   (__float_as_uint(r1) & 0xFFFF0000u);
        }
    }
    o.x = w[0]; o.y = w[1]; o.z = w[2]; o.w = w[3];
    *(uint4*)(wt + (size_t)g * 4) = o;
}

// ---------------------------------------------------------------------------
// Pass 1: 2-plane / 3-pass bf16 MFMA GEMM. Coalesced x staging through a
// transposed LDS tile (xs[k][token]); B via counted-vmcnt gload_lds pipeline.
// Per iter VMEM issue: [X regs (1 dwordx4/thread), S (4 gload_lds/thread)];
// depth 2 -> vmcnt(4) at iter top retires exactly X(kt+1) and S(kt).
// ---------------------------------------------------------------------------
__global__ __launch_bounds__(THREADS, 2) void router_pass1(
    const float* __restrict__ x, const unsigned int* __restrict__ wt,
    const float* __restrict__ b_lin, const float* __restrict__ bias,
    float* __restrict__ out_vals, float* __restrict__ out_idx,
    int* __restrict__ wsI)
{
    __shared__ union {
        struct {
            alignas(16) char B[3 * TILE_B];   // 48 KB: 3 staged B tiles
            float xs[2][16][72];              // 9 KB: x transposed [k][token]
        } t;
        float sc[32 * 260];                   // 33.3 KB: logits (epilogue)
    } sm;

    const int tid  = threadIdx.x;
    const int lane = tid & 63;
    const int wave = tid >> 6;
    const int l31  = lane & 31;
    const int hi   = lane >> 5;
    const int wm   = wave >> 1;
    const int wn   = wave & 1;
    const int t0   = blockIdx.x * BT;

    // x staging identity: token row xtr = tid>>2, k-quad xkq = tid&3
    const int xtr = tid >> 2, xkq = tid & 3;
    const float* xgp = x + (size_t)(t0 + xtr) * DIM + xkq * 4;
    // A-fragment read column: this lane's token
    const int acol = wm * 32 + l31;

    const char* wsrc = (const char*)wt;
    char* bc = sm.t.B;                 // compute buffer (tile kt)
    char* bn = sm.t.B + TILE_B;        // next (kt+1)
    char* bs = sm.t.B + 2 * TILE_B;    // staging (kt+2)

    auto STAGE = [&](char* ldsbase, int kt) {
#pragma unroll
        for (int q = 0; q < 4; ++q) {
            const int chunk = wave * 4 + q;
            gload16(wsrc + (size_t)kt * TILE_B + chunk * 1024 + lane * 16,
                    ldsbase + chunk * 1024);
        }
    };
    auto XWRITE = [&](int b, float4 v) {
        sm.t.xs[b][xkq * 4 + 0][xtr] = v.x;
        sm.t.xs[b][xkq * 4 + 1][xtr] = v.y;
        sm.t.xs[b][xkq * 4 + 2][xtr] = v.z;
        sm.t.xs[b][xkq * 4 + 3][xtr] = v.w;
    };
    auto AFRAG = [&](int b, bf16x8& ah, bf16x8& ar) {
        union { unsigned int u[4]; bf16x8 v; } H, R;
#pragma unroll
        for (int q = 0; q < 4; ++q) {
            const float f0 = sm.t.xs[b][hi * 8 + 2 * q][acol];
            const float f1 = sm.t.xs[b][hi * 8 + 2 * q + 1][acol];
            const unsigned int u0 = __float_as_uint(f0);
            const unsigned int u1 = __float_as_uint(f1);
            H.u[q] = (u0 >> 16) | (u1 & 0xFFFF0000u);
            const float r0 = f0 - __uint_as_float(u0 & 0xFFFF0000u);
            const float r1 = f1 - __uint_as_float(u1 & 0xFFFF0000u);
            R.u[q] = (__float_as_uint(r0) >> 16) |
                     (__float_as_uint(r1) & 0xFFFF0000u);
        }
        ah = H.v; ar = R.v;
    };

    f32x16 acc[4] = {};
    const int e_base = (wn * 128 + l31) * 16;
    const int hi4k   = hi * 4096;

    float4 rA, rB;

    // ---- prologue: X0, S0, X1, S1 ; then pre-write xs[0] ----
    rA = *(const float4*)xgp;                        // X(0)
    __builtin_amdgcn_sched_barrier(0);
    STAGE(bc, 0);                                    // S(0)
    __builtin_amdgcn_sched_barrier(0);
    rB = *(const float4*)(xgp + KT);                 // X(1)
    __builtin_amdgcn_sched_barrier(0);
    STAGE(bn, 1);                                    // S(1)
    __builtin_amdgcn_sched_barrier(0);
    asm volatile("s_waitcnt vmcnt(9)");              // X(0) retired
    __builtin_amdgcn_sched_barrier(0);
    XWRITE(0, rA);

    // one iteration: wrv = X(kt+1) regs, ldv <- X(kt+2)
    auto ITER = [&](int kt, float4 wrv, float4& ldv, bool last) {
        if (!last) asm volatile("s_waitcnt vmcnt(4)");
        else       asm volatile("s_waitcnt vmcnt(0)");
        __builtin_amdgcn_sched_barrier(0);
        asm volatile("s_waitcnt lgkmcnt(0)");
        __builtin_amdgcn_sched_barrier(0);
        __builtin_amdgcn_s_barrier();
        __builtin_amdgcn_sched_barrier(0);
        if (kt + 1 < NKT) XWRITE((kt + 1) & 1, wrv);
        if (kt + 2 < NKT) ldv = *(const float4*)(xgp + (kt + 2) * KT);
        __builtin_amdgcn_sched_barrier(0);
        if (kt + 2 < NKT) STAGE(bs, kt + 2);
        __builtin_amdgcn_sched_barrier(0);

        bf16x8 ah, ar;
        AFRAG(kt & 1, ah, ar);
        __builtin_amdgcn_s_setprio(1);
#pragma unroll
        for (int j = 0; j < 4; ++j) {
            const int eo = e_base + j * 512;
            bf16x8 bh = *(const bf16x8*)(bc + hi4k + eo);
            bf16x8 br = *(const bf16x8*)(bc + 8192 + hi4k + eo);
            acc[j] = __builtin_amdgcn_mfma_f32_32x32x16_bf16(ah, bh, acc[j], 0, 0, 0);
            acc[j] = __builtin_amdgcn_mfma_f32_32x32x16_bf16(ah, br, acc[j], 0, 0, 0);
            acc[j] = __builtin_amdgcn_mfma_f32_32x32x16_bf16(ar, bh, acc[j], 0, 0, 0);
        }
        __builtin_amdgcn_s_setprio(0);
        char* t = bc; bc = bn; bn = bs; bs = t;
    };

    for (int kt2 = 0; kt2 < NKT - 4; kt2 += 2) {
        ITER(kt2,     rB, rA, false);
        ITER(kt2 + 1, rA, rB, false);
    }
    ITER(NKT - 4, rB, rA, false);
    ITER(NKT - 3, rA, rB, false);
    ITER(NKT - 2, rB, rA, false);   // kt+2 == NKT: no new loads issued
    ITER(NKT - 1, rA, rB, true);    // vmcnt(0); no XWRITE

    __syncthreads();   // full drain; LDS reused as sc

    // ---- routing epilogue, two halves of 32 tokens ----
    const int tx = tid & 31;
    const int ty = tid >> 5;
    float blv[8], bsv[8];
#pragma unroll
    for (int j = 0; j < 8; ++j) {
        blv[j] = b_lin[tx + 32 * j];
        bsv[j] = bias[tx + 32 * j];
    }

    for (int h = 0; h < 2; ++h) {
        if (h) __syncthreads();
        if (wm == h) {
#pragma unroll
            for (int j = 0; j < 4; ++j) {
#pragma unroll
                for (int r = 0; r < 16; ++r) {
                    const int row = (r & 3) + 8 * (r >> 2) + 4 * hi;
                    const int e   = wn * 128 + j * 32 + l31;
                    sm.sc[row * 260 + e] = acc[j][r];
                }
            }
        }
        __syncthreads();

#pragma unroll
        for (int i = 0; i < 4; ++i) {
            const int row = ty * 4 + i;
            float s8[8];
            float psum = 0.0f;
#pragma unroll
            for (int j = 0; j < 8; ++j) {
                const float lg = sm.sc[row * 260 + tx + 32 * j] + blv[j];
                const float s = 1.0f / (1.0f + expf(-lg));
                s8[j] = s;
                psum += s;
            }
#pragma unroll
            for (int m = 1; m <= 16; m <<= 1) psum += __shfl_xor(psum, m);
#pragma unroll
            for (int j = 0; j < 8; ++j) s8[j] = s8[j] / psum + bsv[j];

            float gm[8];
#pragma unroll
            for (int j = 0; j < 8; ++j) gm[j] = s8[j];
#pragma unroll
            for (int m = 1; m <= 16; m <<= 1)
#pragma unroll
                for (int j = 0; j < 8; ++j)
                    gm[j] = fmaxf(gm[j], __shfl_xor(gm[j], m));

            unsigned keep = 0u;
            float g4v = 0.0f, g5v = 0.0f;
#pragma unroll
            for (int r = 0; r < 5; ++r) {
                float bv = -1e30f; int bg = 0;
#pragma unroll
                for (int g = 0; g < 8; ++g)
                    if (!((keep >> g) & 1) && gm[g] > bv) { bv = gm[g]; bg = g; }
                if (r < 4) { keep |= 1u << bg; g4v = bv; }
                else g5v = bv;
            }
            float margin = g4v - g5v;

#pragma unroll
            for (int j = 0; j < 8; ++j)
                if (!((keep >> j) & 1)) s8[j] = -1e30f;

            float tv[9]; int te[9];
#pragma unroll
            for (int r = 0; r < 9; ++r) {
                float bv = -1e30f; int bj = 8;
#pragma unroll
                for (int j = 0; j < 8; ++j)
                    if (s8[j] > bv) { bv = s8[j]; bj = j; }
                int be = (bj < 8) ? (tx + 32 * bj) : 9999;
#pragma unroll
                for (int m = 1; m <= 16; m <<= 1) {
                    const float ov = __shfl_xor(bv, m);
                    const int   oe = __shfl_xor(be, m);
                    if (ov > bv || (ov == bv && oe < be)) { bv = ov; be = oe; }
                }
                tv[r] = bv; te[r] = be;
                if (r < 8 && (be & 31) == tx) s8[be >> 5] = -1e30f;
            }
#pragma unroll
            for (int r = 0; r < 8; ++r) margin = fminf(margin, tv[r] - tv[r + 1]);

            if (tx == 0) {
                const int t = t0 + h * 32 + row;
                const int base = t * TOPK;
#pragma unroll
                for (int r = 0; r < 8; ++r) {
                    out_vals[base + r] = tv[r] * RSCALE;
                    out_idx[base + r]  = (float)te[r];
                }
                if (margin < TAU) {
                    const int slot = atomicAdd(&wsI[0], 1);
                    if (slot < 60000) wsI[4 + slot] = t;
                }
            }
        }
    }
}

// ---------------------------------------------------------------------------
// Pass 2: exact fp64 recompute + reroute for margin-flagged tokens.
// ---------------------------------------------------------------------------
__global__ __launch_bounds__(THREADS, 1) void router_pass2(
    const float* __restrict__ x, const float* __restrict__ w1,
    const float* __restrict__ b_lin, const float* __restrict__ bias,
    float* __restrict__ out_vals, float* __restrict__ out_idx,
    const int* __restrict__ wsI)
{
    __shared__ double xrow[DIM];
    __shared__ double red[256];
    __shared__ double sc[NE];

    const int tid = threadIdx.x;
    const int count = min(wsI[0], 60000);
    const int* list = wsI + 4;
    const float4* x4 = (const float4*)x;
    const float4* w4 = (const float4*)w1;

    for (int li = blockIdx.x; li < count; li += gridDim.x) {
        const int t = list[li];
        __syncthreads();
#pragma unroll
        for (int q = 0; q < 2; ++q) {
            const int id = tid + 256 * q;
            const float4 v = x4[t * 512 + id];
            xrow[id * 4 + 0] = (double)v.x;
            xrow[id * 4 + 1] = (double)v.y;
            xrow[id * 4 + 2] = (double)v.z;
            xrow[id * 4 + 3] = (double)v.w;
        }
        __syncthreads();

        const int e = tid;
        double a0 = 0.0, a1 = 0.0, a2 = 0.0, a3 = 0.0;
#pragma unroll 2
        for (int k4 = 0; k4 < 512; k4 += 4) {
#pragma unroll
            for (int z = 0; z < 4; ++z) {
                const float4 wv = w4[e * 512 + k4 + z];
                double* ac = (z == 0) ? &a0 : (z == 1) ? &a1 : (z == 2) ? &a2 : &a3;
                *ac = fma(xrow[(k4 + z) * 4 + 0], (double)wv.x, *ac);
                *ac = fma(xrow[(k4 + z) * 4 + 1], (double)wv.y, *ac);
                *ac = fma(xrow[(k4 + z) * 4 + 2], (double)wv.z, *ac);
                *ac = fma(xrow[(k4 + z) * 4 + 3], (double)wv.w, *ac);
            }
        }
        const double lg = ((a0 + a1) + (a2 + a3)) + (double)b_lin[e];
        const double s = 1.0 / (1.0 + exp(-lg));
        red[tid] = s;
        __syncthreads();
        for (int off = 128; off > 0; off >>= 1) {
            if (tid < off) red[tid] += red[tid + off];
            __syncthreads();
        }
        sc[e] = s / red[0] + (double)bias[e];
        __syncthreads();

        if (tid == 0) {
            double gmax[NG];
            for (int g = 0; g < NG; ++g) {
                double mx = -INFINITY;
                for (int q = 0; q < GSZ; ++q) {
                    const double v = sc[g * GSZ + q];
                    mx = (v > mx) ? v : mx;
                }
                gmax[g] = mx;
            }
            unsigned keep = 0u;
            for (int r = 0; r < NLIM; ++r) {
                int best = 0; double bv = -INFINITY;
                for (int g = 0; g < NG; ++g) {
                    if (keep & (1u << g)) continue;
                    if (gmax[g] > bv) { bv = gmax[g]; best = g; }
                }
                keep |= 1u << best;
            }
            double tv[TOPK]; int ti[TOPK];
            for (int r = 0; r < TOPK; ++r) { tv[r] = -INFINITY; ti[r] = NE; }
            for (int g = 0; g < NG; ++g) {
                if (!(keep & (1u << g))) continue;
                for (int q = 0; q < GSZ; ++q) {
                    const int ee = g * GSZ + q;
                    const double v = sc[ee];
                    if (v > tv[TOPK - 1]) {
                        int p = TOPK - 1;
                        while (p > 0 && v > tv[p - 1]) {
                            tv[p] = tv[p - 1]; ti[p] = ti[p - 1]; --p;
                        }
                        tv[p] = v; ti[p] = ee;
                    }
                }
            }
            const int base = t * TOPK;
            for (int r = 0; r < TOPK; ++r) {
                out_vals[base + r] = (float)(tv[r] * (double)RSCALE);
                out_idx[base + r]  = (float)ti[r];
            }
        }
    }
}

extern "C" void kernel_launch(void* const* d_in, const int* in_sizes, int n_in,
                              void* d_out, int out_size, void* d_ws, size_t ws_size,
                              hipStream_t stream) {
    const float* x     = (const float*)d_in[0];
    const float* w1    = (const float*)d_in[1];
    const float* b_lin = (const float*)d_in[2];
    const float* bias  = (const float*)d_in[3];
    float* out_vals = (float*)d_out;
    float* out_idx  = (float*)d_out + (size_t)NTOK * TOPK;

    int* wsI = (int*)d_ws;
    unsigned int* wt = (unsigned int*)((char*)d_ws + WOFF);

    hipMemsetAsync(d_ws, 0, 16, stream);
    wsplit_kernel<<<dim3(512), 256, 0, stream>>>(w1, wt);
    router_pass1<<<dim3(NTOK / BT), THREADS, 0, stream>>>(
        x, wt, b_lin, bias, out_vals, out_idx, wsI);
    router_pass2<<<dim3(256), THREADS, 0, stream>>>(
        x, w1, b_lin, bias, out_vals, out_idx, (const int*)d_ws);
}